// Round 8
// baseline (348.955 us; speedup 1.0000x reference)
//
#include <hip/hip_runtime.h>

// Partial Radon transform:
//  x: (4, 1, 256, 256) f32 -> out: (4, 5, 256, 180) f32
//
// Round 8 = BISECT of the R6/R7 failure. Two-pass half-image staging kept
// (131 slow-rows x 270 u16 = 70.7 KB -> 2 blocks/CU), but the per-wave
// h-window machinery (hstar division, shfl min/max, readfirstlane, runtime
// loop bounds) is removed: every thread samples ALL h in both passes and the
// exact complementary predicate m = (sl<129)==(pass==0) gates accumulation.
// Coverage is structurally guaranteed; if this fails, the pass/staging core
// is the bug; if it passes, the window logic was.

constexpr int WIDTH  = 256;
constexpr int NANG   = 180;
constexpr int NBATCH = 4;
constexpr int NS     = 5;
constexpr int LSTR   = 270;   // u16 per slow-row (135 dw)
constexpr int LROWS  = 131;   // local slow-rows per pass (incl. zero tail)
constexpr int SPLIT  = 129;   // padded-slow split boundary

__device__ inline unsigned pack2_f16(float a, float b) {
    _Float16 ha = (_Float16)a, hb = (_Float16)b;
    unsigned short ua = __builtin_bit_cast(unsigned short, ha);
    unsigned short ub = __builtin_bit_cast(unsigned short, hb);
    return (unsigned)ua | ((unsigned)ub << 16);
}

__global__ __launch_bounds__(1024, 8) void radon_kernel(const float* __restrict__ x,
                                                        float* __restrict__ out) {
    __shared__ _Float16 lds[LROWS * LSTR];   // 70,740 B

    const int blk = blockIdx.x;          // n * NANG + a
    const int n = blk / NANG;
    const int a = blk - n * NANG;
    const int t = threadIdx.x;
    const int w = t & 255;
    const int q = t >> 8;                // quarter: h-stride phase

    const float* __restrict__ img = x + (size_t)n * WIDTH * WIDTH;

    const float theta = (float)a * 0.017453292519943295f;
    float s, c;
    sincosf(theta, &s, &c);
    const bool transp = (c * c > s * s);

    const float bw  = ((float)w + 0.5f) * (2.0f / WIDTH) - 1.0f;
    const float bh0 = 0.5f * (2.0f / WIDTH) - 1.0f;
    const float gx0 = c * bw + s * bh0;
    const float gy0 = -s * bw + c * bh0;
    const float ix0 = ((gx0 + 1.0f) * (float)WIDTH - 1.0f) * 0.5f;
    const float iy0 = ((gy0 + 1.0f) * (float)WIDTH - 1.0f) * 0.5f;

    // unified (fast, slow) coords; +2 pad folded in
    const float fast0 = (transp ? iy0 : ix0) + 2.0f;
    const float slow0 = (transp ? ix0 : iy0) + 2.0f;
    const float dfast = transp ? c : s;
    const float dslow = transp ? s : c;

    float r0 = 0.f, r1 = 0.f, r2 = 0.f, r3 = 0.f, r4 = 0.f;

    for (int pass = 0; pass < 2; ++pass) {
        // ---- zero LDS ----
        unsigned* l32 = (unsigned*)lds;
        for (int i = t; i < LROWS * LSTR / 2; i += 1024) l32[i] = 0u;
        __syncthreads();

        // ---- stage this pass's half (orig slow rows [127p, ...]) ----
        const int glo = pass ? 127 : 0;          // first orig slow row
        const int robase = 2 - SPLIT * pass;     // local L = orig + robase
        if (!transp) {
            const int nslow = pass ? 129 : 128;
            for (int idx = t; idx < nslow * 128; idx += 1024) {
                const int ys = idx >> 7, xd = idx & 127;
                const int y = glo + ys;
                const float2 v = ((const float2*)img)[y * 128 + xd];
                *(unsigned*)&lds[(y + robase) * LSTR + 2 * xd + 2] = pack2_f16(v.x, v.y);
            }
        } else {
            // slow = x. lanes <-> x (coalesced rows); pack y-pairs.
            const int xi = t & 127;
            const int xx = glo + xi;
            for (int yp = t >> 7; yp < 128; yp += 8) {
                const float v0 = img[(2 * yp) * WIDTH + xx];
                const float v1 = img[(2 * yp + 1) * WIDTH + xx];
                *(unsigned*)&lds[(xx + robase) * LSTR + 2 * yp + 2] = pack2_f16(v0, v1);
                if (pass && xi == 0) {           // 129th slow row (x = 255)
                    const int x2 = glo + 128;
                    const float u0 = img[(2 * yp) * WIDTH + x2];
                    const float u1 = img[(2 * yp + 1) * WIDTH + x2];
                    *(unsigned*)&lds[(x2 + robase) * LSTR + 2 * yp + 2] = pack2_f16(u0, u1);
                }
            }
        }
        __syncthreads();

        auto sample = [&](int h, float& r) {
            const float hf = (float)h;
            float fa = fmaf(hf, dfast, fast0);
            float sl = fmaf(hf, dslow, slow0);
            fa = __builtin_amdgcn_fmed3f(fa, 1.0f, 258.0f);
            sl = __builtin_amdgcn_fmed3f(sl, 1.0f, 258.0f);
            const bool m = (sl < 129.0f) == (pass == 0);   // exact partition
            const float ff = floorf(fa), fs = floorf(sl);
            const float wf = fa - ff, ws = sl - fs;
            const int fi = (int)ff;
            int siL = (int)fs - SPLIT * pass;
            siL = min(max(siL, 0), 129);   // m-true reads exact; m-false junk discarded
            const _Float16* p = &lds[siL * LSTR + fi];
            const float v00 = (float)p[0];
            const float v01 = (float)p[1];
            const float v10 = (float)p[LSTR];
            const float v11 = (float)p[LSTR + 1];
            const float row0 = fmaf(wf, v01 - v00, v00);
            const float row1 = fmaf(wf, v11 - v10, v10);
            const float contrib = fmaf(ws, row1 - row0, row0);
            r += m ? contrib : 0.0f;
        };

        // Ring bands: r4:[0,32)u[224,256)  r3:[32,64)u[192,224)
        //             r2:[64,96)u[160,192) r1:[96,127)u[129,160) r0:[127,129)
        // Full compile-time bounds; quarter q covers h = LO+q, LO+q+4, ...
        #define SEG(LO, HI, R) { \
            for (int h = (LO) + q; h < (HI); h += 4) sample(h, R); }
        SEG(0,   32,  r4)
        SEG(32,  64,  r3)
        SEG(64,  96,  r2)
        SEG(96,  127, r1)
        SEG(127, 129, r0)
        SEG(129, 160, r1)
        SEG(160, 192, r2)
        SEG(192, 224, r3)
        SEG(224, 256, r4)
        #undef SEG

        __syncthreads();   // sampling done before next pass overwrites LDS
    }

    // ---- cross-quarter reduction via LDS reuse ----
    float* red = (float*)lds;              // 1024*5 floats = 20,480 B
    const int base = t * NS;
    red[base + 0] = r0;
    red[base + 1] = r1;
    red[base + 2] = r2;
    red[base + 3] = r3;
    red[base + 4] = r4;
    __syncthreads();

    if (t < 256) {
        const int b0 = t * NS, b1 = b0 + 256 * NS, b2 = b0 + 512 * NS, b3 = b0 + 768 * NS;
        const float s0 = (red[b0+0] + red[b1+0]) + (red[b2+0] + red[b3+0]);
        const float s1 = (red[b0+1] + red[b1+1]) + (red[b2+1] + red[b3+1]);
        const float s2 = (red[b0+2] + red[b1+2]) + (red[b2+2] + red[b3+2]);
        const float s3 = (red[b0+3] + red[b1+3]) + (red[b2+3] + red[b3+3]);
        const float s4 = (red[b0+4] + red[b1+4]) + (red[b2+4] + red[b3+4]);

        float* o = out + (((size_t)n * NS) * WIDTH + (size_t)t) * NANG + (size_t)a;
        float cum = s0;
        o[0]                          = cum * (1.0f / 2.0f);
        cum += s1;
        o[(size_t)1 * WIDTH * NANG]   = cum * (1.0f / 64.0f);
        cum += s2;
        o[(size_t)2 * WIDTH * NANG]   = cum * (1.0f / 128.0f);
        cum += s3;
        o[(size_t)3 * WIDTH * NANG]   = cum * (1.0f / 192.0f);
        cum += s4;
        o[(size_t)4 * WIDTH * NANG]   = cum * (1.0f / 256.0f);
    }
}

extern "C" void kernel_launch(void* const* d_in, const int* in_sizes, int n_in,
                              void* d_out, int out_size, void* d_ws, size_t ws_size,
                              hipStream_t stream) {
    const float* x = (const float*)d_in[0];
    float* out = (float*)d_out;
    radon_kernel<<<NBATCH * NANG, 1024, 0, stream>>>(x, out);
}

// Round 9
// 182.281 us; speedup vs baseline: 1.9144x; 1.9144x over previous
//
#include <hip/hip_runtime.h>

// Partial Radon transform:
//  x: (4, 1, 256, 256) f32 -> out: (4, 5, 256, 180) f32
//
// Round 9 = R5 (known-good single-pass, 61 us) + two measured fixes:
//  (a) XCD-aware inverse block swizzle: consecutive (n,a) share an XCD so
//      the stride-720B output stores merge into full 64B lines in that
//      XCD's L2 (R5: WRITE_SIZE 29 MB vs 3.4 MB useful, ~8x amplification
//      from round-robin XCD dispatch).
//  (b) compile-time trip counts (for k<8, h = BASE+q+4k) so the sample
//      loops fully unroll -> 8 independent ds_read chains in flight
//      (R5's runtime-trip loops defeated the unroll; R8 showed serialized
//      ds_reads are the latency killer). r1-band re-cut on 32-boundaries
//      with wave-uniform h==127/128 select into r0.

constexpr int WIDTH  = 256;
constexpr int NANG   = 180;
constexpr int NBATCH = 4;
constexpr int NS     = 5;
constexpr int LSTR   = 270;   // u16 per slow-row: 540 B, 135 dw, 135%32=7
constexpr int ROWS   = 260;   // padded slow extent

__device__ inline unsigned pack2_f16(float a, float b) {
    _Float16 ha = (_Float16)a, hb = (_Float16)b;
    unsigned short ua = __builtin_bit_cast(unsigned short, ha);
    unsigned short ub = __builtin_bit_cast(unsigned short, hb);
    return (unsigned)ua | ((unsigned)ub << 16);
}

__global__ __launch_bounds__(1024) void radon_kernel(const float* __restrict__ x,
                                                     float* __restrict__ out) {
    __shared__ _Float16 lds[ROWS * LSTR];   // 140,400 B static

    // XCD-aware inverse swizzle (720 = 8 XCDs x 90): blocks with the same
    // bid&7 run on one XCD; give each XCD a contiguous run of (n,a).
    const int bid = blockIdx.x;
    const int lin = (bid & 7) * 90 + (bid >> 3);   // bijective on [0,720)
    const int n = lin / NANG;
    const int a = lin - n * NANG;
    const int t = threadIdx.x;
    const int w = t & 255;
    const int q = t >> 8;                // quarter: h-stride phase

    const float* __restrict__ img = x + (size_t)n * WIDTH * WIDTH;

    const float theta = (float)a * 0.017453292519943295f;
    float s, c;
    sincosf(theta, &s, &c);
    const bool transp = (c * c > s * s);

    // ---- Zero-fill LDS (borders + pad) ----
    unsigned* l32 = (unsigned*)lds;
    for (int i = t; i < ROWS * LSTR / 2; i += 1024) l32[i] = 0u;
    __syncthreads();

    // ---- Stage image (interior at padded +2), layout chosen per block ----
    if (!transp) {
        for (int d = t; d < 32768; d += 1024) {
            const int y = d >> 7, xd = d & 127;
            const float2 v = ((const float2*)img)[d];
            *(unsigned*)&lds[(y + 2) * LSTR + 2 * xd + 2] = pack2_f16(v.x, v.y);
        }
    } else {
        for (int yp = q; yp < 128; yp += 4) {
            const int y = 2 * yp;
            const float v0 = img[y * WIDTH + w];
            const float v1 = img[y * WIDTH + WIDTH + w];
            *(unsigned*)&lds[(w + 2) * LSTR + y + 2] = pack2_f16(v0, v1);
        }
    }
    __syncthreads();

    // ---- Per-(a,w) line walk ----
    const float bw  = ((float)w + 0.5f) * (2.0f / WIDTH) - 1.0f;
    const float bh0 = 0.5f * (2.0f / WIDTH) - 1.0f;
    const float gx0 = c * bw + s * bh0;
    const float gy0 = -s * bw + c * bh0;
    const float ix0 = ((gx0 + 1.0f) * (float)WIDTH - 1.0f) * 0.5f;
    const float iy0 = ((gy0 + 1.0f) * (float)WIDTH - 1.0f) * 0.5f;

    const float fast0 = (transp ? iy0 : ix0) + 2.0f;
    const float slow0 = (transp ? ix0 : iy0) + 2.0f;
    const float dfast = transp ? c : s;
    const float dslow = transp ? s : c;

    float r0 = 0.f, r1 = 0.f, r2 = 0.f, r3 = 0.f, r4 = 0.f;

    auto sample = [&](int h) -> float {
        const float hf = (float)h;
        float fa = fmaf(hf, dfast, fast0);
        float sl = fmaf(hf, dslow, slow0);
        fa = __builtin_amdgcn_fmed3f(fa, 1.0f, 258.0f);
        sl = __builtin_amdgcn_fmed3f(sl, 1.0f, 258.0f);
        const float ff = floorf(fa), fs = floorf(sl);
        const float wf = fa - ff, ws = sl - fs;
        const int fi = (int)ff, si = (int)fs;
        const _Float16* p = &lds[si * LSTR + fi];
        const float v00 = (float)p[0];
        const float v01 = (float)p[1];
        const float v10 = (float)p[LSTR];
        const float v11 = (float)p[LSTR + 1];
        const float row0 = fmaf(wf, v01 - v00, v00);
        const float row1 = fmaf(wf, v11 - v10, v10);
        return fmaf(ws, row1 - row0, row0);
    };

    // Ring bands (disjoint): r4:[0,32)u[224,256) r3:[32,64)u[192,224)
    // r2:[64,96)u[160,192)  r1:[96,160)\{127,128}  r0:{127,128}
    // All loops: compile-time trip count 8 -> full unroll, 8 chains in flight.
    #pragma unroll
    for (int k = 0; k < 8; ++k) r4 += sample(q + 4 * k);
    #pragma unroll
    for (int k = 0; k < 8; ++k) r3 += sample(32 + q + 4 * k);
    #pragma unroll
    for (int k = 0; k < 8; ++k) r2 += sample(64 + q + 4 * k);
    #pragma unroll
    for (int k = 0; k < 8; ++k) {
        const int h = 96 + q + 4 * k;
        const float v = sample(h);
        if (h == 127) r0 += v; else r1 += v;   // wave-uniform branch (q,k)
    }
    #pragma unroll
    for (int k = 0; k < 8; ++k) {
        const int h = 128 + q + 4 * k;
        const float v = sample(h);
        if (h == 128) r0 += v; else r1 += v;   // wave-uniform branch (q,k)
    }
    #pragma unroll
    for (int k = 0; k < 8; ++k) r2 += sample(160 + q + 4 * k);
    #pragma unroll
    for (int k = 0; k < 8; ++k) r3 += sample(192 + q + 4 * k);
    #pragma unroll
    for (int k = 0; k < 8; ++k) r4 += sample(224 + q + 4 * k);

    // ---- Cross-quarter reduction via LDS reuse ----
    __syncthreads();                       // sampling done; image dead
    float* red = (float*)lds;              // 1024*5 floats = 20,480 B
    const int base = t * NS;
    red[base + 0] = r0;
    red[base + 1] = r1;
    red[base + 2] = r2;
    red[base + 3] = r3;
    red[base + 4] = r4;
    __syncthreads();

    if (t < 256) {
        const int b0 = t * NS, b1 = b0 + 256 * NS, b2 = b0 + 512 * NS, b3 = b0 + 768 * NS;
        const float s0 = (red[b0+0] + red[b1+0]) + (red[b2+0] + red[b3+0]);
        const float s1 = (red[b0+1] + red[b1+1]) + (red[b2+1] + red[b3+1]);
        const float s2 = (red[b0+2] + red[b1+2]) + (red[b2+2] + red[b3+2]);
        const float s3 = (red[b0+3] + red[b1+3]) + (red[b2+3] + red[b3+3]);
        const float s4 = (red[b0+4] + red[b1+4]) + (red[b2+4] + red[b3+4]);

        float* o = out + (((size_t)n * NS) * WIDTH + (size_t)t) * NANG + (size_t)a;
        float cum = s0;
        o[0]                          = cum * (1.0f / 2.0f);
        cum += s1;
        o[(size_t)1 * WIDTH * NANG]   = cum * (1.0f / 64.0f);
        cum += s2;
        o[(size_t)2 * WIDTH * NANG]   = cum * (1.0f / 128.0f);
        cum += s3;
        o[(size_t)3 * WIDTH * NANG]   = cum * (1.0f / 192.0f);
        cum += s4;
        o[(size_t)4 * WIDTH * NANG]   = cum * (1.0f / 256.0f);
    }
}

extern "C" void kernel_launch(void* const* d_in, const int* in_sizes, int n_in,
                              void* d_out, int out_size, void* d_ws, size_t ws_size,
                              hipStream_t stream) {
    const float* x = (const float*)d_in[0];
    float* out = (float*)d_out;
    radon_kernel<<<NBATCH * NANG, 1024, 0, stream>>>(x, out);
}

// Round 10
// 58.043 us; speedup vs baseline: 6.0120x; 3.1404x over previous
//
#include <hip/hip_runtime.h>

// Partial Radon transform:
//  x: (4, 1, 256, 256) f32 -> out: (4, 5, 256, 180) f32
//
// Round 10 = R5 structure verbatim (known-good 61 us) + two changes:
//  (a) XCD swizzle kept from R9 (validated: WRITE_SIZE 29->7.9 MB; innocent
//      in the R9 regression — scheduling identical, only (n,a) relabeled).
//  (b) pair-cell LDS: each dword holds pixels (2j,2j+1) as 2xf16. A bilinear
//      row fetch = 2 adjacent ds_read_b32 (merge to ds_read2_b32) + funnel
//      shift by 16*(fi&1) -> 2 DS instr/sample instead of 4 ds_read_u16.
//      260 rows x 131 dwords = 136,240 B; stride 131 == 3 (mod 32).
//  R9's loop restructure (strided-h full unroll) is NOT retained — it
//  serialized the DS chains (VALU 53->18%, 3x regression).

constexpr int WIDTH  = 256;
constexpr int NANG   = 180;
constexpr int NBATCH = 4;
constexpr int NS     = 5;
constexpr int CSTR   = 131;   // dword cells per slow-row; 131%32=3
constexpr int ROWS   = 260;   // padded slow extent: pad 0,1 | orig 2..257 | pad 258,259

__device__ inline unsigned pack2_f16(float a, float b) {
    _Float16 ha = (_Float16)a, hb = (_Float16)b;
    unsigned short ua = __builtin_bit_cast(unsigned short, ha);
    unsigned short ub = __builtin_bit_cast(unsigned short, hb);
    return (unsigned)ua | ((unsigned)ub << 16);
}

__global__ __launch_bounds__(1024) void radon_kernel(const float* __restrict__ x,
                                                     float* __restrict__ out) {
    __shared__ unsigned cells[ROWS * CSTR];   // 136,240 B static

    // XCD-aware swizzle (720 = 8 XCDs x 90): same-XCD blocks get contiguous
    // (n,a) so stride-720B output stores merge into full lines in its L2.
    const int bid = blockIdx.x;
    const int lin = (bid & 7) * 90 + (bid >> 3);   // bijective on [0,720)
    const int n = lin / NANG;
    const int a = lin - n * NANG;
    const int t = threadIdx.x;
    const int w = t & 255;
    const int quarter = t >> 8;          // contiguous 64-h range per quarter

    const float* __restrict__ img = x + (size_t)n * WIDTH * WIDTH;

    const float theta = (float)a * 0.017453292519943295f;
    float s, c;
    sincosf(theta, &s, &c);
    const bool transp = (c * c > s * s);

    // ---- Zero-fill LDS (borders + pad) ----
    for (int i = t; i < ROWS * CSTR; i += 1024) cells[i] = 0u;
    __syncthreads();

    // ---- Stage image; cell (row, c) = padded-fast pixels (2c, 2c+1) ----
    if (!transp) {
        // slow=y, fast=x: cell c = orig x (2c-2, 2c-1) -> c = xd+1
        for (int d = t; d < 32768; d += 1024) {
            const int y = d >> 7, xd = d & 127;
            const float2 v = ((const float2*)img)[d];
            cells[(y + 2) * CSTR + xd + 1] = pack2_f16(v.x, v.y);
        }
    } else {
        // slow=x, fast=y: lane<->x (coalesced rows); cell c = orig y (2c-2,2c-1)
        for (int yp = quarter; yp < 128; yp += 4) {
            const float v0 = img[(2 * yp) * WIDTH + w];
            const float v1 = img[(2 * yp + 1) * WIDTH + w];
            cells[(w + 2) * CSTR + yp + 1] = pack2_f16(v0, v1);
        }
    }
    __syncthreads();

    // ---- Per-(a,w) line walk ----
    const float bw  = ((float)w + 0.5f) * (2.0f / WIDTH) - 1.0f;
    const float bh0 = 0.5f * (2.0f / WIDTH) - 1.0f;
    const float gx0 = c * bw + s * bh0;
    const float gy0 = -s * bw + c * bh0;
    const float ix0 = ((gx0 + 1.0f) * (float)WIDTH - 1.0f) * 0.5f;
    const float iy0 = ((gy0 + 1.0f) * (float)WIDTH - 1.0f) * 0.5f;

    const float fast0 = (transp ? iy0 : ix0) + 2.0f;
    const float slow0 = (transp ? ix0 : iy0) + 2.0f;
    const float dfast = transp ? c : s;
    const float dslow = transp ? s : c;

    float r0 = 0.f, r1 = 0.f, r2 = 0.f, r3 = 0.f, r4 = 0.f;

    auto sample = [&](int h, float& r) {
        const float hf = (float)h;
        float fa = fmaf(hf, dfast, fast0);
        float sl = fmaf(hf, dslow, slow0);
        fa = __builtin_amdgcn_fmed3f(fa, 1.0f, 258.0f);
        sl = __builtin_amdgcn_fmed3f(sl, 1.0f, 258.0f);
        const float ff = floorf(fa), fs = floorf(sl);
        const float wf = fa - ff, ws = sl - fs;
        const int fi = (int)ff, si = (int)fs;
        const int j = fi >> 1;
        const int sh = (fi & 1) << 4;
        const unsigned* rowA = &cells[si * CSTR + j];
        const unsigned loA = rowA[0],    hiA = rowA[1];
        const unsigned loB = rowA[CSTR], hiB = rowA[CSTR + 1];
        const unsigned pairA = (unsigned)(((((unsigned long long)hiA) << 32) | loA) >> sh);
        const unsigned pairB = (unsigned)(((((unsigned long long)hiB) << 32) | loB) >> sh);
        const float v00 = (float)__builtin_bit_cast(_Float16, (unsigned short)pairA);
        const float v01 = (float)__builtin_bit_cast(_Float16, (unsigned short)(pairA >> 16));
        const float v10 = (float)__builtin_bit_cast(_Float16, (unsigned short)pairB);
        const float v11 = (float)__builtin_bit_cast(_Float16, (unsigned short)(pairB >> 16));
        const float row0 = fmaf(wf, v01 - v00, v00);
        const float row1 = fmaf(wf, v11 - v10, v10);
        r = fmaf(ws, row1 - row0, r + 0.0f * row0), r = fmaf(ws, row1 - row0, row0) + r - fmaf(ws, row1 - row0, row0) + fmaf(ws, row1 - row0, row0);
    };

    // NOTE: the line above must be a plain accumulate; keep it simple:
    // (replaced below — see sample2)
    auto sample2 = [&](int h, float& r) {
        const float hf = (float)h;
        float fa = fmaf(hf, dfast, fast0);
        float sl = fmaf(hf, dslow, slow0);
        fa = __builtin_amdgcn_fmed3f(fa, 1.0f, 258.0f);
        sl = __builtin_amdgcn_fmed3f(sl, 1.0f, 258.0f);
        const float ff = floorf(fa), fs = floorf(sl);
        const float wf = fa - ff, ws = sl - fs;
        const int fi = (int)ff, si = (int)fs;
        const int j = fi >> 1;
        const int sh = (fi & 1) << 4;
        const unsigned* rowA = &cells[si * CSTR + j];
        const unsigned loA = rowA[0],    hiA = rowA[1];
        const unsigned loB = rowA[CSTR], hiB = rowA[CSTR + 1];
        const unsigned pairA = (unsigned)(((((unsigned long long)hiA) << 32) | loA) >> sh);
        const unsigned pairB = (unsigned)(((((unsigned long long)hiB) << 32) | loB) >> sh);
        const float v00 = (float)__builtin_bit_cast(_Float16, (unsigned short)pairA);
        const float v01 = (float)__builtin_bit_cast(_Float16, (unsigned short)(pairA >> 16));
        const float v10 = (float)__builtin_bit_cast(_Float16, (unsigned short)pairB);
        const float v11 = (float)__builtin_bit_cast(_Float16, (unsigned short)(pairB >> 16));
        const float row0 = fmaf(wf, v01 - v00, v00);
        const float row1 = fmaf(wf, v11 - v10, v10);
        r += fmaf(ws, row1 - row0, row0);
    };
    (void)sample;

    // Ring bands (R5 segmentation, contiguous h per quarter):
    //  r4:[0,32)u[224,256)  r3:[32,64)u[192,224)
    //  r2:[64,96)u[160,192) r1:[96,127)u[129,160) r0:{127,128}
    if (quarter == 0) {
        #pragma unroll 8
        for (int h = 0; h < 32; ++h)    sample2(h, r4);
        #pragma unroll 8
        for (int h = 32; h < 64; ++h)   sample2(h, r3);
    } else if (quarter == 1) {
        #pragma unroll 8
        for (int h = 64; h < 96; ++h)   sample2(h, r2);
        #pragma unroll 8
        for (int h = 96; h < 127; ++h)  sample2(h, r1);
        sample2(127, r0);
    } else if (quarter == 2) {
        sample2(128, r0);
        #pragma unroll 8
        for (int h = 129; h < 160; ++h) sample2(h, r1);
        #pragma unroll 8
        for (int h = 160; h < 192; ++h) sample2(h, r2);
    } else {
        #pragma unroll 8
        for (int h = 192; h < 224; ++h) sample2(h, r3);
        #pragma unroll 8
        for (int h = 224; h < 256; ++h) sample2(h, r4);
    }

    // ---- Cross-quarter reduction via LDS reuse ----
    __syncthreads();                       // sampling done; image dead
    float* red = (float*)cells;            // 1024*5 floats = 20,480 B
    const int base = t * NS;
    red[base + 0] = r0;
    red[base + 1] = r1;
    red[base + 2] = r2;
    red[base + 3] = r3;
    red[base + 4] = r4;
    __syncthreads();

    if (t < 256) {
        const int b0 = t * NS, b1 = b0 + 256 * NS, b2 = b0 + 512 * NS, b3 = b0 + 768 * NS;
        const float s0 = (red[b0+0] + red[b1+0]) + (red[b2+0] + red[b3+0]);
        const float s1 = (red[b0+1] + red[b1+1]) + (red[b2+1] + red[b3+1]);
        const float s2 = (red[b0+2] + red[b1+2]) + (red[b2+2] + red[b3+2]);
        const float s3 = (red[b0+3] + red[b1+3]) + (red[b2+3] + red[b3+3]);
        const float s4 = (red[b0+4] + red[b1+4]) + (red[b2+4] + red[b3+4]);

        float* o = out + (((size_t)n * NS) * WIDTH + (size_t)t) * NANG + (size_t)a;
        float cum = s0;
        o[0]                          = cum * (1.0f / 2.0f);
        cum += s1;
        o[(size_t)1 * WIDTH * NANG]   = cum * (1.0f / 64.0f);
        cum += s2;
        o[(size_t)2 * WIDTH * NANG]   = cum * (1.0f / 128.0f);
        cum += s3;
        o[(size_t)3 * WIDTH * NANG]   = cum * (1.0f / 192.0f);
        cum += s4;
        o[(size_t)4 * WIDTH * NANG]   = cum * (1.0f / 256.0f);
    }
}

extern "C" void kernel_launch(void* const* d_in, const int* in_sizes, int n_in,
                              void* d_out, int out_size, void* d_ws, size_t ws_size,
                              hipStream_t stream) {
    const float* x = (const float*)d_in[0];
    float* out = (float*)d_out;
    radon_kernel<<<NBATCH * NANG, 1024, 0, stream>>>(x, out);
}

// Round 11
// 51.413 us; speedup vs baseline: 6.7873x; 1.1290x over previous
//
#include <hip/hip_runtime.h>

// Partial Radon transform:
//  x: (4, 1, 256, 256) f32 -> out: (4, 5, 256, 180) f32
//
// Round 11 = R10 structure (58 us) + per-sample VALU cuts (VALU is the
// measured top pipe: 62% busy, ~40 us of 64):
//  (a) v_alignbit_b32 for the f16-pair select (replaces 64-bit funnel shift)
//  (b) fract/trunc-cvt for weights+indices (saves floor/sub pairs)
//  (c) packed-f16 cross-row lerp (v_pk_fma_f16): col = (vb-va)*ws + va,
//      then one f32 lerp along fast axis. Adds ~0.005-0.01 abs error
//      (budget: threshold 0.0516, R10 absmax 0.0156).
//  (d) zero-fill pad cells only (interior fully overwritten by staging).
// Unchanged: XCD swizzle (WRITE 29->3.8 MB validated), pair-cell LDS
// (CSTR=131), quarter h-ranges, unroll 8, reduction epilogue.

constexpr int WIDTH  = 256;
constexpr int NANG   = 180;
constexpr int NBATCH = 4;
constexpr int NS     = 5;
constexpr int CSTR   = 131;   // dword cells per slow-row; 131%32=3
constexpr int ROWS   = 260;   // padded slow: pad 0,1 | orig 2..257 | pad 258,259

typedef _Float16 h2 __attribute__((ext_vector_type(2)));

#if __has_builtin(__builtin_amdgcn_fractf)
#define FRACT(x) __builtin_amdgcn_fractf(x)
#else
#define FRACT(x) ((x) - floorf(x))
#endif

__device__ inline unsigned pack2_f16(float a, float b) {
    _Float16 ha = (_Float16)a, hb = (_Float16)b;
    unsigned short ua = __builtin_bit_cast(unsigned short, ha);
    unsigned short ub = __builtin_bit_cast(unsigned short, hb);
    return (unsigned)ua | ((unsigned)ub << 16);
}

__global__ __launch_bounds__(1024) void radon_kernel(const float* __restrict__ x,
                                                     float* __restrict__ out) {
    __shared__ unsigned cells[ROWS * CSTR];   // 136,240 B static

    // XCD-aware swizzle (720 = 8 XCDs x 90): same-XCD blocks get contiguous
    // (n,a) so stride-720B output stores merge into full lines in its L2.
    const int bid = blockIdx.x;
    const int lin = (bid & 7) * 90 + (bid >> 3);   // bijective on [0,720)
    const int n = lin / NANG;
    const int a = lin - n * NANG;
    const int t = threadIdx.x;
    const int w = t & 255;
    const int quarter = t >> 8;          // contiguous 64-h range per quarter

    const float* __restrict__ img = x + (size_t)n * WIDTH * WIDTH;

    const float theta = (float)a * 0.017453292519943295f;
    float s, c;
    sincosf(theta, &s, &c);
    const bool transp = (c * c > s * s);

    // ---- Zero-fill pad cells only (interior is fully staged below) ----
    for (int i = t; i < 2 * CSTR; i += 1024) {       // rows 0,1
        cells[i] = 0u;
        cells[258 * CSTR + i] = 0u;                  // rows 258,259
    }
    if (t < ROWS) {                                  // cols j=0,129,130, all rows
        const int b = t * CSTR;
        cells[b] = 0u; cells[b + 129] = 0u; cells[b + 130] = 0u;
    }
    __syncthreads();

    // ---- Stage image; cell (row, c) = padded-fast pixels (2c, 2c+1) ----
    if (!transp) {
        // slow=y, fast=x: cell c = orig x (2c-2, 2c-1) -> c = xd+1
        for (int d = t; d < 32768; d += 1024) {
            const int y = d >> 7, xd = d & 127;
            const float2 v = ((const float2*)img)[d];
            cells[(y + 2) * CSTR + xd + 1] = pack2_f16(v.x, v.y);
        }
    } else {
        // slow=x, fast=y: lane<->x (coalesced rows); cell c = orig y (2c-2,2c-1)
        for (int yp = quarter; yp < 128; yp += 4) {
            const float v0 = img[(2 * yp) * WIDTH + w];
            const float v1 = img[(2 * yp + 1) * WIDTH + w];
            cells[(w + 2) * CSTR + yp + 1] = pack2_f16(v0, v1);
        }
    }
    __syncthreads();

    // ---- Per-(a,w) line walk ----
    const float bw  = ((float)w + 0.5f) * (2.0f / WIDTH) - 1.0f;
    const float bh0 = 0.5f * (2.0f / WIDTH) - 1.0f;
    const float gx0 = c * bw + s * bh0;
    const float gy0 = -s * bw + c * bh0;
    const float ix0 = ((gx0 + 1.0f) * (float)WIDTH - 1.0f) * 0.5f;
    const float iy0 = ((gy0 + 1.0f) * (float)WIDTH - 1.0f) * 0.5f;

    const float fast0 = (transp ? iy0 : ix0) + 2.0f;
    const float slow0 = (transp ? ix0 : iy0) + 2.0f;
    const float dfast = transp ? c : s;
    const float dslow = transp ? s : c;

    float r0 = 0.f, r1 = 0.f, r2 = 0.f, r3 = 0.f, r4 = 0.f;

    auto sample = [&](int h, float& r) {
        const float hf = (float)h;
        float fa = fmaf(hf, dfast, fast0);
        float sl = fmaf(hf, dslow, slow0);
        fa = __builtin_amdgcn_fmed3f(fa, 1.0f, 258.0f);
        sl = __builtin_amdgcn_fmed3f(sl, 1.0f, 258.0f);
        const int fi = (int)fa, si = (int)sl;   // trunc == floor (coords >= 1)
        const float wf = FRACT(fa);
        const float ws = FRACT(sl);
        const int j = fi >> 1;
        const int sh = (fi & 1) << 4;
        const unsigned* rowA = &cells[__mul24(si, CSTR) + j];
        const unsigned loA = rowA[0],    hiA = rowA[1];
        const unsigned loB = rowA[CSTR], hiB = rowA[CSTR + 1];
        const unsigned pa = __builtin_amdgcn_alignbit(hiA, loA, sh); // {v00,v01}
        const unsigned pb = __builtin_amdgcn_alignbit(hiB, loB, sh); // {v10,v11}
        const h2 va = __builtin_bit_cast(h2, pa);
        const h2 vb = __builtin_bit_cast(h2, pb);
        const _Float16 wsh = (_Float16)ws;
        const h2 ws2 = {wsh, wsh};
        const h2 col = (vb - va) * ws2 + va;    // packed lerp along slow axis
        const float c0 = (float)col.x;
        const float c1 = (float)col.y;
        r += fmaf(wf, c1 - c0, c0);             // f32 lerp along fast axis
    };

    // Ring bands (R5/R10 segmentation, contiguous h per quarter):
    //  r4:[0,32)u[224,256)  r3:[32,64)u[192,224)
    //  r2:[64,96)u[160,192) r1:[96,127)u[129,160) r0:{127,128}
    if (quarter == 0) {
        #pragma unroll 8
        for (int h = 0; h < 32; ++h)    sample(h, r4);
        #pragma unroll 8
        for (int h = 32; h < 64; ++h)   sample(h, r3);
    } else if (quarter == 1) {
        #pragma unroll 8
        for (int h = 64; h < 96; ++h)   sample(h, r2);
        #pragma unroll 8
        for (int h = 96; h < 127; ++h)  sample(h, r1);
        sample(127, r0);
    } else if (quarter == 2) {
        sample(128, r0);
        #pragma unroll 8
        for (int h = 129; h < 160; ++h) sample(h, r1);
        #pragma unroll 8
        for (int h = 160; h < 192; ++h) sample(h, r2);
    } else {
        #pragma unroll 8
        for (int h = 192; h < 224; ++h) sample(h, r3);
        #pragma unroll 8
        for (int h = 224; h < 256; ++h) sample(h, r4);
    }

    // ---- Cross-quarter reduction via LDS reuse ----
    __syncthreads();                       // sampling done; image dead
    float* red = (float*)cells;            // 1024*5 floats = 20,480 B
    const int base = t * NS;
    red[base + 0] = r0;
    red[base + 1] = r1;
    red[base + 2] = r2;
    red[base + 3] = r3;
    red[base + 4] = r4;
    __syncthreads();

    if (t < 256) {
        const int b0 = t * NS, b1 = b0 + 256 * NS, b2 = b0 + 512 * NS, b3 = b0 + 768 * NS;
        const float s0 = (red[b0+0] + red[b1+0]) + (red[b2+0] + red[b3+0]);
        const float s1 = (red[b0+1] + red[b1+1]) + (red[b2+1] + red[b3+1]);
        const float s2 = (red[b0+2] + red[b1+2]) + (red[b2+2] + red[b3+2]);
        const float s3 = (red[b0+3] + red[b1+3]) + (red[b2+3] + red[b3+3]);
        const float s4 = (red[b0+4] + red[b1+4]) + (red[b2+4] + red[b3+4]);

        float* o = out + (((size_t)n * NS) * WIDTH + (size_t)t) * NANG + (size_t)a;
        float cum = s0;
        o[0]                          = cum * (1.0f / 2.0f);
        cum += s1;
        o[(size_t)1 * WIDTH * NANG]   = cum * (1.0f / 64.0f);
        cum += s2;
        o[(size_t)2 * WIDTH * NANG]   = cum * (1.0f / 128.0f);
        cum += s3;
        o[(size_t)3 * WIDTH * NANG]   = cum * (1.0f / 192.0f);
        cum += s4;
        o[(size_t)4 * WIDTH * NANG]   = cum * (1.0f / 256.0f);
    }
}

extern "C" void kernel_launch(void* const* d_in, const int* in_sizes, int n_in,
                              void* d_out, int out_size, void* d_ws, size_t ws_size,
                              hipStream_t stream) {
    const float* x = (const float*)d_in[0];
    float* out = (float*)d_out;
    radon_kernel<<<NBATCH * NANG, 1024, 0, stream>>>(x, out);
}

// Round 12
// 49.844 us; speedup vs baseline: 7.0010x; 1.0315x over previous
//
#include <hip/hip_runtime.h>

// Partial Radon transform:
//  x: (4, 1, 256, 256) f32 -> out: (4, 5, 256, 180) f32
//
// Round 12 = R11 (51 us) with identical iteration space, deeper ILP:
//  (a) unroll 16 on uniform 32-trip sample loops (VGPR 52 of 128 budget ->
//      room for ~2x more independent DS chains per wave; VALU was 54% busy,
//      latency-bound remainder). Ring r0 handled by per-copy select.
//  (b) zero-fill + staging merged before ONE barrier (disjoint addr sets).
//  (c) float4 staging on the non-transposed path (16 iters, adjacent cells).
// Unchanged: XCD swizzle, pair-cell LDS (CSTR=131), quarter h-ranges,
// alignbit/fract/packed-lerp sample, reduction epilogue.

constexpr int WIDTH  = 256;
constexpr int NANG   = 180;
constexpr int NBATCH = 4;
constexpr int NS     = 5;
constexpr int CSTR   = 131;   // dword cells per slow-row; 131%32=3
constexpr int ROWS   = 260;   // padded slow: pad 0,1 | orig 2..257 | pad 258,259

typedef _Float16 h2 __attribute__((ext_vector_type(2)));

#if __has_builtin(__builtin_amdgcn_fractf)
#define FRACT(x) __builtin_amdgcn_fractf(x)
#else
#define FRACT(x) ((x) - floorf(x))
#endif

__device__ inline unsigned pack2_f16(float a, float b) {
    _Float16 ha = (_Float16)a, hb = (_Float16)b;
    unsigned short ua = __builtin_bit_cast(unsigned short, ha);
    unsigned short ub = __builtin_bit_cast(unsigned short, hb);
    return (unsigned)ua | ((unsigned)ub << 16);
}

__global__ __launch_bounds__(1024) void radon_kernel(const float* __restrict__ x,
                                                     float* __restrict__ out) {
    __shared__ unsigned cells[ROWS * CSTR];   // 136,240 B static

    // XCD-aware swizzle (720 = 8 XCDs x 90): same-XCD blocks get contiguous
    // (n,a) so stride-720B output stores merge into full lines in its L2.
    const int bid = blockIdx.x;
    const int lin = (bid & 7) * 90 + (bid >> 3);   // bijective on [0,720)
    const int n = lin / NANG;
    const int a = lin - n * NANG;
    const int t = threadIdx.x;
    const int w = t & 255;
    const int quarter = t >> 8;          // contiguous 64-h range per quarter

    const float* __restrict__ img = x + (size_t)n * WIDTH * WIDTH;

    const float theta = (float)a * 0.017453292519943295f;
    float s, c;
    sincosf(theta, &s, &c);
    const bool transp = (c * c > s * s);

    // ---- Zero-fill pad cells + stage interior: DISJOINT sets, one barrier ----
    for (int i = t; i < 2 * CSTR; i += 1024) {       // rows 0,1 and 258,259
        cells[i] = 0u;
        cells[258 * CSTR + i] = 0u;
    }
    if (t < ROWS) {                                  // cols j=0,129,130, all rows
        const int b = t * CSTR;
        cells[b] = 0u; cells[b + 129] = 0u; cells[b + 130] = 0u;
    }

    if (!transp) {
        // slow=y, fast=x. float4 = 4 px = 2 adjacent cells. Coalesced 16B reads.
        #pragma unroll
        for (int i = 0; i < 16; ++i) {
            const int d = t + 1024 * i;              // float4 index in [0,16384)
            const float4 v = ((const float4*)img)[d];
            const int y  = d >> 6;                   // row
            const int j0 = ((d & 63) << 1) + 1;      // first cell (pad +1)
            const int base = (y + 2) * CSTR + j0;
            cells[base]     = pack2_f16(v.x, v.y);
            cells[base + 1] = pack2_f16(v.z, v.w);
        }
    } else {
        // slow=x, fast=y: lane<->x (coalesced rows); cell c = orig y (2c-2,2c-1)
        for (int yp = quarter; yp < 128; yp += 4) {
            const float v0 = img[(2 * yp) * WIDTH + w];
            const float v1 = img[(2 * yp + 1) * WIDTH + w];
            cells[(w + 2) * CSTR + yp + 1] = pack2_f16(v0, v1);
        }
    }
    __syncthreads();

    // ---- Per-(a,w) line walk ----
    const float bw  = ((float)w + 0.5f) * (2.0f / WIDTH) - 1.0f;
    const float bh0 = 0.5f * (2.0f / WIDTH) - 1.0f;
    const float gx0 = c * bw + s * bh0;
    const float gy0 = -s * bw + c * bh0;
    const float ix0 = ((gx0 + 1.0f) * (float)WIDTH - 1.0f) * 0.5f;
    const float iy0 = ((gy0 + 1.0f) * (float)WIDTH - 1.0f) * 0.5f;

    const float fast0 = (transp ? iy0 : ix0) + 2.0f;
    const float slow0 = (transp ? ix0 : iy0) + 2.0f;
    const float dfast = transp ? c : s;
    const float dslow = transp ? s : c;

    float r0 = 0.f, r1 = 0.f, r2 = 0.f, r3 = 0.f, r4 = 0.f;

    auto sample = [&](int h) -> float {
        const float hf = (float)h;
        float fa = fmaf(hf, dfast, fast0);
        float sl = fmaf(hf, dslow, slow0);
        fa = __builtin_amdgcn_fmed3f(fa, 1.0f, 258.0f);
        sl = __builtin_amdgcn_fmed3f(sl, 1.0f, 258.0f);
        const int fi = (int)fa, si = (int)sl;   // trunc == floor (coords >= 1)
        const float wf = FRACT(fa);
        const float ws = FRACT(sl);
        const int j = fi >> 1;
        const int sh = (fi & 1) << 4;
        const unsigned* rowA = &cells[__mul24(si, CSTR) + j];
        const unsigned loA = rowA[0],    hiA = rowA[1];
        const unsigned loB = rowA[CSTR], hiB = rowA[CSTR + 1];
        const unsigned pa = __builtin_amdgcn_alignbit(hiA, loA, sh); // {v00,v01}
        const unsigned pb = __builtin_amdgcn_alignbit(hiB, loB, sh); // {v10,v11}
        const h2 va = __builtin_bit_cast(h2, pa);
        const h2 vb = __builtin_bit_cast(h2, pb);
        const _Float16 wsh = (_Float16)ws;
        const h2 ws2 = {wsh, wsh};
        const h2 col = (vb - va) * ws2 + va;    // packed lerp along slow axis
        const float c0 = (float)col.x;
        const float c1 = (float)col.y;
        return fmaf(wf, c1 - c0, c0);           // f32 lerp along fast axis
    };

    // Ring bands: r4:[0,32)u[224,256)  r3:[32,64)u[192,224)
    //             r2:[64,96)u[160,192) r1:[96,127)u[129,160) r0:{127,128}
    // Uniform 32-trip loops, unroll 16; r0 via per-copy select.
    if (quarter == 0) {
        #pragma unroll 16
        for (int k = 0; k < 32; ++k) r4 += sample(k);
        #pragma unroll 16
        for (int k = 0; k < 32; ++k) r3 += sample(32 + k);
    } else if (quarter == 1) {
        #pragma unroll 16
        for (int k = 0; k < 32; ++k) r2 += sample(64 + k);
        #pragma unroll 16
        for (int k = 0; k < 32; ++k) {
            const float v = sample(96 + k);
            if (k == 31) r0 += v; else r1 += v;   // h==127
        }
    } else if (quarter == 2) {
        #pragma unroll 16
        for (int k = 0; k < 32; ++k) {
            const float v = sample(128 + k);
            if (k == 0) r0 += v; else r1 += v;    // h==128
        }
        #pragma unroll 16
        for (int k = 0; k < 32; ++k) r2 += sample(160 + k);
    } else {
        #pragma unroll 16
        for (int k = 0; k < 32; ++k) r3 += sample(192 + k);
        #pragma unroll 16
        for (int k = 0; k < 32; ++k) r4 += sample(224 + k);
    }

    // ---- Cross-quarter reduction via LDS reuse ----
    __syncthreads();                       // sampling done; image dead
    float* red = (float*)cells;            // 1024*5 floats = 20,480 B
    const int base = t * NS;
    red[base + 0] = r0;
    red[base + 1] = r1;
    red[base + 2] = r2;
    red[base + 3] = r3;
    red[base + 4] = r4;
    __syncthreads();

    if (t < 256) {
        const int b0 = t * NS, b1 = b0 + 256 * NS, b2 = b0 + 512 * NS, b3 = b0 + 768 * NS;
        const float s0 = (red[b0+0] + red[b1+0]) + (red[b2+0] + red[b3+0]);
        const float s1 = (red[b0+1] + red[b1+1]) + (red[b2+1] + red[b3+1]);
        const float s2 = (red[b0+2] + red[b1+2]) + (red[b2+2] + red[b3+2]);
        const float s3 = (red[b0+3] + red[b1+3]) + (red[b2+3] + red[b3+3]);
        const float s4 = (red[b0+4] + red[b1+4]) + (red[b2+4] + red[b3+4]);

        float* o = out + (((size_t)n * NS) * WIDTH + (size_t)t) * NANG + (size_t)a;
        float cum = s0;
        o[0]                          = cum * (1.0f / 2.0f);
        cum += s1;
        o[(size_t)1 * WIDTH * NANG]   = cum * (1.0f / 64.0f);
        cum += s2;
        o[(size_t)2 * WIDTH * NANG]   = cum * (1.0f / 128.0f);
        cum += s3;
        o[(size_t)3 * WIDTH * NANG]   = cum * (1.0f / 192.0f);
        cum += s4;
        o[(size_t)4 * WIDTH * NANG]   = cum * (1.0f / 256.0f);
    }
}

extern "C" void kernel_launch(void* const* d_in, const int* in_sizes, int n_in,
                              void* d_out, int out_size, void* d_ws, size_t ws_size,
                              hipStream_t stream) {
    const float* x = (const float*)d_in[0];
    float* out = (float*)d_out;
    radon_kernel<<<NBATCH * NANG, 1024, 0, stream>>>(x, out);
}